// Round 10
// baseline (1087.953 us; speedup 1.0000x reference)
//
#include <hip/hip_runtime.h>
#include <hip/hip_bf16.h>
#include <float.h>
#include <math.h>

typedef __hip_bfloat16 bf16;

#define NEGBIG (-1e30f)

__device__ __forceinline__ float ldv(const bf16* p, int i) { return __bfloat162float(p[i]); }
__device__ __forceinline__ float ldv(const float* p, int i) { return p[i]; }
__device__ __forceinline__ void stv(float* p, int i, float v) { p[i] = v; }
__device__ __forceinline__ void stv(bf16* p, int i, float v) { p[i] = __float2bfloat16(v); }

__device__ __forceinline__ float wave_sum(float v) {
#pragma unroll
  for (int off = 32; off; off >>= 1) v += __shfl_xor(v, off, 64);
  return v;
}
__device__ __forceinline__ float wave_max(float v) {
#pragma unroll
  for (int off = 32; off; off >>= 1) v = fmaxf(v, __shfl_xor(v, off, 64));
  return v;
}

// 2-chain dot of q (LDS float4) with one K row (global, L2-resident).
__device__ __forceinline__ float dot64(const float4* __restrict__ qr,
                                       const float4* __restrict__ kr) {
  float d0 = 0.f, d1 = 0.f;
#pragma unroll
  for (int i = 0; i < 16; ++i) {
    float4 a = qr[i], b = kr[i];
    d0 += a.x * b.x + a.z * b.z;
    d1 += a.y * b.y + a.w * b.w;
  }
  return d0 + d1;
}

// ---------------- generic tiled GEMM: C(MxN) = A(MxK) @ B(KxN), f32 accum ----
template <typename TA, typename TB, typename TC>
__global__ __launch_bounds__(256) void gemm_tile(
    const TA* __restrict__ A, const TB* __restrict__ B, TC* __restrict__ C,
    int M, int N, int K, int lda, int ldb, int ldc)
{
  __shared__ float As[16][65];
  __shared__ float Bs[16][65];
  const int tid = threadIdx.x;
  const int tx = tid & 15, ty = tid >> 4;
  const int row0 = blockIdx.y * 64, col0 = blockIdx.x * 64;
  float acc[4][4] = {};
  for (int k0 = 0; k0 < K; k0 += 16) {
#pragma unroll
    for (int l = 0; l < 4; ++l) {
      int idx = tid + l * 256;
      int m = idx >> 4, kk = idx & 15;
      As[kk][m] = ldv(A, (row0 + m) * lda + k0 + kk);
      int kk2 = idx >> 6, n = idx & 63;
      Bs[kk2][n] = ldv(B, (k0 + kk2) * ldb + col0 + n);
    }
    __syncthreads();
#pragma unroll
    for (int kk = 0; kk < 16; ++kk) {
      float a[4], b[4];
#pragma unroll
      for (int i = 0; i < 4; ++i) a[i] = As[kk][ty * 4 + i];
#pragma unroll
      for (int j = 0; j < 4; ++j) b[j] = Bs[kk][tx * 4 + j];
#pragma unroll
      for (int i = 0; i < 4; ++i)
#pragma unroll
        for (int j = 0; j < 4; ++j) acc[i][j] += a[i] * b[j];
    }
    __syncthreads();
  }
#pragma unroll
  for (int i = 0; i < 4; ++i)
#pragma unroll
    for (int j = 0; j < 4; ++j)
      stv(C, (row0 + ty * 4 + i) * ldc + col0 + tx * 4 + j, acc[i][j]);
}

// ---------------- RoPE (first 32 dims) + RMSNorm, one wave per 64-dim row ----
__global__ __launch_bounds__(256) void rope_rms_kernel(
    float* __restrict__ x, const float* __restrict__ g, int rows, int posShift)
{
  const int lane = threadIdx.x & 63;
  const int wid = threadIdx.x >> 6;
  const int r = blockIdx.x * 4 + wid;
  if (r >= rows) return;
  const int pos = r >> posShift;
  float val = x[r * 64 + lane];
  float p = __shfl_xor(val, 16, 64);
  float out = val;
  if (lane < 32) {
    int i = lane & 15;
    double ang = (double)pos * pow(10000.0, -(double)i / 16.0);
    float cc = (float)cos(ang), ss = (float)sin(ang);
    out = (lane < 16) ? (val * cc - p * ss) : (p * ss + val * cc);
  }
  float ms = wave_sum(out * out) * (1.0f / 64.0f);
  float rn = rsqrtf(ms + 1e-6f);
  x[r * 64 + lane] = out * rn * ldv(g, lane);
}

// ---------------- block-mean compression: kc/vc (64 blocks x 64 dims) --------
__global__ void compress_kernel(const float* __restrict__ k, const float* __restrict__ v,
                                float* __restrict__ kc, float* __restrict__ vc)
{
  const int n = blockIdx.x;   // block index 0..63
  const int d = threadIdx.x;  // dim 0..63
  float sk = 0.f, sv = 0.f;
  for (int j = 0; j < 32; ++j) {
    sk += k[(n * 32 + j) * 64 + d];
    sv += v[(n * 32 + j) * 64 + d];
  }
  kc[n * 64 + d] = sk * (1.0f / 32.0f);
  vc[n * 64 + d] = sv * (1.0f / 32.0f);
}

// ---------------- attention: one wave per (qpos, head) -----------------------
// No K/V staging (r5 vs r9 A/B: staging is latency-neutral, costs VGPR+LDS+barriers).
// shfl-broadcast PV with 4 chains (r9's real win). Zero __syncthreads. LDS ~2.5KB.
__global__ __launch_bounds__(256) void attn_kernel(
    const float* __restrict__ q, const float* __restrict__ kbuf, const float* __restrict__ vbuf,
    const float* __restrict__ kc, const float* __restrict__ vc,
    const float* __restrict__ w_gate, const float* __restrict__ b_gate,
    const float* __restrict__ sink, float* __restrict__ mixed)
{
  __shared__ __align__(16) float shq[4][64];
  __shared__ int shsel[4][16];
  const int lane = threadIdx.x & 63;
  const int wid = threadIdx.x >> 6;
  const int r = blockIdx.x * 4 + wid;   // r = qpos*8 + h
  const int qpos = r >> 3, h = r & 7;
  const float scale = 0.125f;

  float qv = q[r * 64 + lane];
  shq[wid][lane] = qv;

  // ---- gate: sigmoid(q @ w_gate + b_gate), normalized ----
  float z0 = qv * ldv(w_gate, lane * 3 + 0);
  float z1 = qv * ldv(w_gate, lane * 3 + 1);
  float z2 = qv * ldv(w_gate, lane * 3 + 2);
  z0 = wave_sum(z0) + ldv(b_gate, 0);
  z1 = wave_sum(z1) + ldv(b_gate, 1);
  z2 = wave_sum(z2) + ldv(b_gate, 2);
  float ga0 = 1.f / (1.f + expf(-z0));
  float ga1 = 1.f / (1.f + expf(-z1));
  float ga2 = 1.f / (1.f + expf(-z2));
  float gs = fmaxf(ga0 + ga1 + ga2, 1e-6f);
  float ginv = 1.f / gs;
  ga0 *= ginv; ga1 *= ginv; ga2 *= ginv;

  const float4* qr = reinterpret_cast<const float4*>(&shq[wid][0]);
  const float snk = ldv(sink, h);
  const int nv = (qpos + 1) >> 5;  // valid compressed blocks

  // ---- compressed scores (lane = block index) ----
  float sc = dot64(qr, reinterpret_cast<const float4*>(kc + lane * 64)) * scale;

  float comp_out = 0.f;
  if (nv > 0) {
    float scomp = (lane < nv) ? sc : NEGBIG;
    float m = fmaxf(wave_max(scomp), snk);
    float e = (lane < nv) ? expf(sc - m) : 0.f;
    float S = wave_sum(e) + expf(snk - m);
    float pn = e / S;   // zero for lane >= nv
    float c0 = 0.f, c1 = 0.f, c2 = 0.f, c3 = 0.f;
#pragma unroll
    for (int n = 0; n < 64; n += 4) {
      float p0 = __shfl(pn, n + 0, 64);
      float p1 = __shfl(pn, n + 1, 64);
      float p2 = __shfl(pn, n + 2, 64);
      float p3 = __shfl(pn, n + 3, 64);
      c0 += p0 * vc[(n + 0) * 64 + lane];
      c1 += p1 * vc[(n + 1) * 64 + lane];
      c2 += p2 * vc[(n + 2) * 64 + lane];
      c3 += p3 * vc[(n + 3) * 64 + lane];
    }
    comp_out = (c0 + c1) + (c2 + c3);
  }

  // ---- top-16 block selection (emulates jax.lax.top_k tie semantics) ----
  {
    float selv = (lane < nv) ? sc : -FLT_MAX;   // invalid = -FLT_MAX (picked by index order)
#pragma unroll
    for (int it = 0; it < 16; ++it) {
      float bv = selv; int bi = lane;
#pragma unroll
      for (int off = 32; off; off >>= 1) {
        float ov = __shfl_xor(bv, off, 64);
        int oi = __shfl_xor(bi, off, 64);
        if (ov > bv || (ov == bv && oi < bi)) { bv = ov; bi = oi; }
      }
      if (lane == 0) shsel[wid][it] = bi;
      if (lane == bi) selv = -INFINITY;         // removed, never re-picked
    }
  }

  // ---- selected branch: 16 chunks of one 32-token block each ----
  // QK direct from global (L2-resident; scattered reads measured latency-neutral).
  float M = NEGBIG, S = 0.f, osel = 0.f;
  for (int c = 0; c < 16; ++c) {
    int b = shsel[wid][c];
    int tokbase = b * 32;
    int tok = tokbase + (lane & 31);
    bool ok = (lane < 32) && (tok <= qpos);
    float s = NEGBIG;
    if (ok) s = dot64(qr, reinterpret_cast<const float4*>(kbuf + tok * 64)) * scale;
    float Mn = fmaxf(M, wave_max(s));
    float e = ok ? expf(s - Mn) : 0.f;
    float cs = wave_sum(e);
    float corr = expf(M - Mn);
    S = S * corr + cs;
    float a0 = 0.f, a1 = 0.f, a2 = 0.f, a3 = 0.f;
#pragma unroll
    for (int l = 0; l < 32; l += 4) {
      float p0 = __shfl(e, l + 0, 64);
      float p1 = __shfl(e, l + 1, 64);
      float p2 = __shfl(e, l + 2, 64);
      float p3 = __shfl(e, l + 3, 64);
      a0 += p0 * vbuf[(tokbase + l + 0) * 64 + lane];
      a1 += p1 * vbuf[(tokbase + l + 1) * 64 + lane];
      a2 += p2 * vbuf[(tokbase + l + 2) * 64 + lane];
      a3 += p3 * vbuf[(tokbase + l + 3) * 64 + lane];
    }
    osel = osel * corr + ((a0 + a1) + (a2 + a3));
    M = Mn;
  }
  osel /= S;

  // ---- sliding-window branch (window 512, with sink) ----
  float Mw = NEGBIG, Sw = 0.f, osw = 0.f;
  int kstart = qpos - 511; if (kstart < 0) kstart = 0;
  int nch = (qpos - kstart + 64) >> 6;
  for (int c = 0; c < nch; ++c) {
    int base = kstart + c * 64;
    int tok = base + lane;
    bool ok = (tok <= qpos);
    float s = NEGBIG;
    if (ok) s = dot64(qr, reinterpret_cast<const float4*>(kbuf + tok * 64)) * scale;
    float Mn = fmaxf(Mw, wave_max(s));
    float e = ok ? expf(s - Mn) : 0.f;
    float cs = wave_sum(e);
    float corr = expf(Mw - Mn);
    Sw = Sw * corr + cs;
    float a0 = 0.f, a1 = 0.f, a2 = 0.f, a3 = 0.f;
#pragma unroll
    for (int l = 0; l < 64; l += 4) {
      float p0 = __shfl(e, l + 0, 64);
      float p1 = __shfl(e, l + 1, 64);
      float p2 = __shfl(e, l + 2, 64);
      float p3 = __shfl(e, l + 3, 64);
      a0 += p0 * vbuf[(base + l + 0) * 64 + lane];
      a1 += p1 * vbuf[(base + l + 1) * 64 + lane];
      a2 += p2 * vbuf[(base + l + 2) * 64 + lane];
      a3 += p3 * vbuf[(base + l + 3) * 64 + lane];
    }
    osw = osw * corr + ((a0 + a1) + (a2 + a3));
    Mw = Mn;
  }
  {
    float Mf = fmaxf(Mw, snk);
    float corr = expf(Mw - Mf);
    float Sf = Sw * corr + expf(snk - Mf);
    osw = osw * corr / Sf;
  }

  mixed[r * 64 + lane] = ga0 * comp_out + ga1 * osel + ga2 * osw;
}

// ---------------- launch ----------------
extern "C" void kernel_launch(void* const* d_in, const int* in_sizes, int n_in,
                              void* d_out, int out_size, void* d_ws, size_t ws_size,
                              hipStream_t stream) {
  const float* h      = (const float*)d_in[0];
  const float* w_qc   = (const float*)d_in[1];
  const float* w_qup  = (const float*)d_in[2];
  const float* w_k    = (const float*)d_in[3];
  const float* w_v    = (const float*)d_in[4];
  const float* g_qn   = (const float*)d_in[5];
  const float* g_kn   = (const float*)d_in[6];
  const float* w_gate = (const float*)d_in[7];
  const float* b_gate = (const float*)d_in[8];
  const float* sink   = (const float*)d_in[9];
  const float* wog    = (const float*)d_in[10];
  const float* w_out  = (const float*)d_in[11];
  float* out = (float*)d_out;

  float* ws = (float*)d_ws;
  float* hc = ws;                    // 2048*256
  float* qb = hc + 2048 * 256;       // 2048*512  (t, h, d)
  float* kb = qb + 2048 * 512;       // 2048*64
  float* vb = kb + 2048 * 64;        // 2048*64
  float* kc = vb + 2048 * 64;        // 64*64
  float* vc = kc + 64 * 64;          // 64*64
  float* mx = vc + 64 * 64;          // 2048*512  (t, h, d)
  float* y1 = mx + 2048 * 512;       // 2048*1024

  dim3 blk(256);
  // hc = h @ w_qc
  gemm_tile<float, float, float><<<dim3(4, 32), blk, 0, stream>>>(h, w_qc, hc, 2048, 256, 1024, 1024, 256, 256);
  // q_raw = hc @ w_qup
  gemm_tile<float, float, float><<<dim3(8, 32), blk, 0, stream>>>(hc, w_qup, qb, 2048, 512, 256, 256, 512, 512);
  // k_raw = h @ w_k ; v = h @ w_v
  gemm_tile<float, float, float><<<dim3(1, 32), blk, 0, stream>>>(h, w_k, kb, 2048, 64, 1024, 1024, 64, 64);
  gemm_tile<float, float, float><<<dim3(1, 32), blk, 0, stream>>>(h, w_v, vb, 2048, 64, 1024, 1024, 64, 64);
  // RoPE + RMSNorm
  rope_rms_kernel<<<dim3(4096), blk, 0, stream>>>(qb, g_qn, 16384, 3);
  rope_rms_kernel<<<dim3(512), blk, 0, stream>>>(kb, g_kn, 2048, 0);
  // compressed K/V
  compress_kernel<<<dim3(64), dim3(64), 0, stream>>>(kb, vb, kc, vc);
  // attention (comp + selected + sliding window + gate mix)
  attn_kernel<<<dim3(4096), blk, 0, stream>>>(qb, kb, vb, kc, vc, w_gate, b_gate, sink, mx);
  // grouped projection: y1[:, g*512:(g+1)*512] = mx[:, g*256:(g+1)*256] @ wog[g]
  gemm_tile<float, float, float><<<dim3(8, 32), blk, 0, stream>>>(mx, wog, y1, 2048, 512, 256, 512, 512, 1024);
  gemm_tile<float, float, float><<<dim3(8, 32), blk, 0, stream>>>(mx + 256, wog + 256 * 512, y1 + 512, 2048, 512, 256, 512, 512, 1024);
  // out = y1 @ w_out  (f32 store)
  gemm_tile<float, float, float><<<dim3(16, 32), blk, 0, stream>>>(y1, w_out, out, 2048, 1024, 1024, 1024, 1024, 1024);
}

// Round 11
// 1050.545 us; speedup vs baseline: 1.0356x; 1.0356x over previous
//
#include <hip/hip_runtime.h>
#include <hip/hip_bf16.h>
#include <float.h>
#include <math.h>

typedef __hip_bfloat16 bf16;

#define NEGBIG (-1e30f)

__device__ __forceinline__ float ldv(const bf16* p, int i) { return __bfloat162float(p[i]); }
__device__ __forceinline__ float ldv(const float* p, int i) { return p[i]; }
__device__ __forceinline__ void stv(float* p, int i, float v) { p[i] = v; }
__device__ __forceinline__ void stv(bf16* p, int i, float v) { p[i] = __float2bfloat16(v); }

__device__ __forceinline__ float wave_sum(float v) {
#pragma unroll
  for (int off = 32; off; off >>= 1) v += __shfl_xor(v, off, 64);
  return v;
}
__device__ __forceinline__ float wave_max(float v) {
#pragma unroll
  for (int off = 32; off; off >>= 1) v = fmaxf(v, __shfl_xor(v, off, 64));
  return v;
}

// Low-register dot: batches of 2 float4 (8 K-regs in flight), unroll 1.
// Same d0/d1 chain order as the old dot64 -> numerically identical.
__device__ __forceinline__ float dot64(const float4* __restrict__ qr,
                                       const float4* __restrict__ kr) {
  float d0 = 0.f, d1 = 0.f;
#pragma unroll 1
  for (int b = 0; b < 8; ++b) {
    float4 a0 = qr[b * 2 + 0], k0 = kr[b * 2 + 0];
    float4 a1 = qr[b * 2 + 1], k1 = kr[b * 2 + 1];
    d0 += a0.x * k0.x + a0.z * k0.z;
    d1 += a0.y * k0.y + a0.w * k0.w;
    d0 += a1.x * k1.x + a1.z * k1.z;
    d1 += a1.y * k1.y + a1.w * k1.w;
  }
  return d0 + d1;
}

// ---------------- generic tiled GEMM: C(MxN) = A(MxK) @ B(KxN), f32 accum ----
template <typename TA, typename TB, typename TC>
__global__ __launch_bounds__(256) void gemm_tile(
    const TA* __restrict__ A, const TB* __restrict__ B, TC* __restrict__ C,
    int M, int N, int K, int lda, int ldb, int ldc)
{
  __shared__ float As[16][65];
  __shared__ float Bs[16][65];
  const int tid = threadIdx.x;
  const int tx = tid & 15, ty = tid >> 4;
  const int row0 = blockIdx.y * 64, col0 = blockIdx.x * 64;
  float acc[4][4] = {};
  for (int k0 = 0; k0 < K; k0 += 16) {
#pragma unroll
    for (int l = 0; l < 4; ++l) {
      int idx = tid + l * 256;
      int m = idx >> 4, kk = idx & 15;
      As[kk][m] = ldv(A, (row0 + m) * lda + k0 + kk);
      int kk2 = idx >> 6, n = idx & 63;
      Bs[kk2][n] = ldv(B, (k0 + kk2) * ldb + col0 + n);
    }
    __syncthreads();
#pragma unroll
    for (int kk = 0; kk < 16; ++kk) {
      float a[4], b[4];
#pragma unroll
      for (int i = 0; i < 4; ++i) a[i] = As[kk][ty * 4 + i];
#pragma unroll
      for (int j = 0; j < 4; ++j) b[j] = Bs[kk][tx * 4 + j];
#pragma unroll
      for (int i = 0; i < 4; ++i)
#pragma unroll
        for (int j = 0; j < 4; ++j) acc[i][j] += a[i] * b[j];
    }
    __syncthreads();
  }
#pragma unroll
  for (int i = 0; i < 4; ++i)
#pragma unroll
    for (int j = 0; j < 4; ++j)
      stv(C, (row0 + ty * 4 + i) * ldc + col0 + tx * 4 + j, acc[i][j]);
}

// ---------------- RoPE (first 32 dims) + RMSNorm, one wave per 64-dim row ----
__global__ __launch_bounds__(256) void rope_rms_kernel(
    float* __restrict__ x, const float* __restrict__ g, int rows, int posShift)
{
  const int lane = threadIdx.x & 63;
  const int wid = threadIdx.x >> 6;
  const int r = blockIdx.x * 4 + wid;
  if (r >= rows) return;
  const int pos = r >> posShift;
  float val = x[r * 64 + lane];
  float p = __shfl_xor(val, 16, 64);
  float out = val;
  if (lane < 32) {
    int i = lane & 15;
    double ang = (double)pos * pow(10000.0, -(double)i / 16.0);
    float cc = (float)cos(ang), ss = (float)sin(ang);
    out = (lane < 16) ? (val * cc - p * ss) : (p * ss + val * cc);
  }
  float ms = wave_sum(out * out) * (1.0f / 64.0f);
  float rn = rsqrtf(ms + 1e-6f);
  x[r * 64 + lane] = out * rn * ldv(g, lane);
}

// ---------------- block-mean compression: kc/vc (64 blocks x 64 dims) --------
__global__ void compress_kernel(const float* __restrict__ k, const float* __restrict__ v,
                                float* __restrict__ kc, float* __restrict__ vc)
{
  const int n = blockIdx.x;   // block index 0..63
  const int d = threadIdx.x;  // dim 0..63
  float sk = 0.f, sv = 0.f;
  for (int j = 0; j < 32; ++j) {
    sk += k[(n * 32 + j) * 64 + d];
    sv += v[(n * 32 + j) * 64 + d];
  }
  kc[n * 64 + d] = sk * (1.0f / 32.0f);
  vc[n * 64 + d] = sv * (1.0f / 32.0f);
}

// ---------------- attention: one wave per (qpos, head) -----------------------
// shfl-broadcast PV (r9 win) + low-register restructure: unroll-1 batched QK
// loads and unroll-1 PV groups to stay under the 64-VGPR occupancy cliff
// (r5 vs r10: latency 1.65x better with shfl-PV, but VGPR 112 halved waves).
__global__ __launch_bounds__(256) void attn_kernel(
    const float* __restrict__ q, const float* __restrict__ kbuf, const float* __restrict__ vbuf,
    const float* __restrict__ kc, const float* __restrict__ vc,
    const float* __restrict__ w_gate, const float* __restrict__ b_gate,
    const float* __restrict__ sink, float* __restrict__ mixed)
{
  __shared__ __align__(16) float shq[4][64];
  __shared__ int shsel[4][16];
  const int lane = threadIdx.x & 63;
  const int wid = threadIdx.x >> 6;
  const int r = blockIdx.x * 4 + wid;   // r = qpos*8 + h
  const int qpos = r >> 3, h = r & 7;
  const float scale = 0.125f;

  float qv = q[r * 64 + lane];
  shq[wid][lane] = qv;

  // ---- gate: sigmoid(q @ w_gate + b_gate), normalized ----
  float z0 = qv * ldv(w_gate, lane * 3 + 0);
  float z1 = qv * ldv(w_gate, lane * 3 + 1);
  float z2 = qv * ldv(w_gate, lane * 3 + 2);
  z0 = wave_sum(z0) + ldv(b_gate, 0);
  z1 = wave_sum(z1) + ldv(b_gate, 1);
  z2 = wave_sum(z2) + ldv(b_gate, 2);
  float ga0 = 1.f / (1.f + expf(-z0));
  float ga1 = 1.f / (1.f + expf(-z1));
  float ga2 = 1.f / (1.f + expf(-z2));
  float gs = fmaxf(ga0 + ga1 + ga2, 1e-6f);
  float ginv = 1.f / gs;
  ga0 *= ginv; ga1 *= ginv; ga2 *= ginv;

  const float4* qr = reinterpret_cast<const float4*>(&shq[wid][0]);
  const float snk = ldv(sink, h);
  const int nv = (qpos + 1) >> 5;  // valid compressed blocks

  // ---- compressed scores (lane = block index) ----
  float sc = dot64(qr, reinterpret_cast<const float4*>(kc + lane * 64)) * scale;

  float comp_out = 0.f;
  if (nv > 0) {
    float scomp = (lane < nv) ? sc : NEGBIG;
    float m = fmaxf(wave_max(scomp), snk);
    float e = (lane < nv) ? expf(sc - m) : 0.f;
    float S = wave_sum(e) + expf(snk - m);
    float pn = e / S;   // zero for lane >= nv
    float c0 = 0.f, c1 = 0.f, c2 = 0.f, c3 = 0.f;
#pragma unroll 1
    for (int n = 0; n < 64; n += 4) {
      float p0 = __shfl(pn, n + 0, 64);
      float p1 = __shfl(pn, n + 1, 64);
      float p2 = __shfl(pn, n + 2, 64);
      float p3 = __shfl(pn, n + 3, 64);
      c0 += p0 * vc[(n + 0) * 64 + lane];
      c1 += p1 * vc[(n + 1) * 64 + lane];
      c2 += p2 * vc[(n + 2) * 64 + lane];
      c3 += p3 * vc[(n + 3) * 64 + lane];
    }
    comp_out = (c0 + c1) + (c2 + c3);
  }

  // ---- top-16 block selection (emulates jax.lax.top_k tie semantics) ----
  {
    float selv = (lane < nv) ? sc : -FLT_MAX;   // invalid = -FLT_MAX (picked by index order)
#pragma unroll
    for (int it = 0; it < 16; ++it) {
      float bv = selv; int bi = lane;
#pragma unroll
      for (int off = 32; off; off >>= 1) {
        float ov = __shfl_xor(bv, off, 64);
        int oi = __shfl_xor(bi, off, 64);
        if (ov > bv || (ov == bv && oi < bi)) { bv = ov; bi = oi; }
      }
      if (lane == 0) shsel[wid][it] = bi;
      if (lane == bi) selv = -INFINITY;         // removed, never re-picked
    }
  }

  // ---- selected branch: 16 chunks of one 32-token block each ----
  float M = NEGBIG, S = 0.f, osel = 0.f;
#pragma unroll 1
  for (int c = 0; c < 16; ++c) {
    int b = shsel[wid][c];
    int tokbase = b * 32;
    if (tokbase > qpos) continue;   // no valid token in block: e==0 for all lanes, state unchanged
    int tok = tokbase + (lane & 31);
    bool ok = (lane < 32) && (tok <= qpos);
    float s = NEGBIG;
    if (ok) s = dot64(qr, reinterpret_cast<const float4*>(kbuf + tok * 64)) * scale;
    float Mn = fmaxf(M, wave_max(s));
    float e = ok ? expf(s - Mn) : 0.f;
    float cs = wave_sum(e);
    float corr = expf(M - Mn);
    S = S * corr + cs;
    float a0 = 0.f, a1 = 0.f, a2 = 0.f, a3 = 0.f;
#pragma unroll 1
    for (int l = 0; l < 32; l += 4) {
      float p0 = __shfl(e, l + 0, 64);
      float p1 = __shfl(e, l + 1, 64);
      float p2 = __shfl(e, l + 2, 64);
      float p3 = __shfl(e, l + 3, 64);
      a0 += p0 * vbuf[(tokbase + l + 0) * 64 + lane];
      a1 += p1 * vbuf[(tokbase + l + 1) * 64 + lane];
      a2 += p2 * vbuf[(tokbase + l + 2) * 64 + lane];
      a3 += p3 * vbuf[(tokbase + l + 3) * 64 + lane];
    }
    osel = osel * corr + ((a0 + a1) + (a2 + a3));
    M = Mn;
  }
  osel /= S;

  // ---- sliding-window branch (window 512, with sink) ----
  float Mw = NEGBIG, Sw = 0.f, osw = 0.f;
  int kstart = qpos - 511; if (kstart < 0) kstart = 0;
  int nch = (qpos - kstart + 64) >> 6;
#pragma unroll 1
  for (int c = 0; c < nch; ++c) {
    int base = kstart + c * 64;
    int tok = base + lane;
    bool ok = (tok <= qpos);
    float s = NEGBIG;
    if (ok) s = dot64(qr, reinterpret_cast<const float4*>(kbuf + tok * 64)) * scale;
    float Mn = fmaxf(Mw, wave_max(s));
    float e = ok ? expf(s - Mn) : 0.f;
    float cs = wave_sum(e);
    float corr = expf(Mw - Mn);
    Sw = Sw * corr + cs;
    float a0 = 0.f, a1 = 0.f, a2 = 0.f, a3 = 0.f;
#pragma unroll 1
    for (int l = 0; l < 64; l += 4) {
      float p0 = __shfl(e, l + 0, 64);
      float p1 = __shfl(e, l + 1, 64);
      float p2 = __shfl(e, l + 2, 64);
      float p3 = __shfl(e, l + 3, 64);
      a0 += p0 * vbuf[(base + l + 0) * 64 + lane];
      a1 += p1 * vbuf[(base + l + 1) * 64 + lane];
      a2 += p2 * vbuf[(base + l + 2) * 64 + lane];
      a3 += p3 * vbuf[(base + l + 3) * 64 + lane];
    }
    osw = osw * corr + ((a0 + a1) + (a2 + a3));
    Mw = Mn;
  }
  {
    float Mf = fmaxf(Mw, snk);
    float corr = expf(Mw - Mf);
    float Sf = Sw * corr + expf(snk - Mf);
    osw = osw * corr / Sf;
  }

  mixed[r * 64 + lane] = ga0 * comp_out + ga1 * osel + ga2 * osw;
}

// ---------------- launch ----------------
extern "C" void kernel_launch(void* const* d_in, const int* in_sizes, int n_in,
                              void* d_out, int out_size, void* d_ws, size_t ws_size,
                              hipStream_t stream) {
  const float* h      = (const float*)d_in[0];
  const float* w_qc   = (const float*)d_in[1];
  const float* w_qup  = (const float*)d_in[2];
  const float* w_k    = (const float*)d_in[3];
  const float* w_v    = (const float*)d_in[4];
  const float* g_qn   = (const float*)d_in[5];
  const float* g_kn   = (const float*)d_in[6];
  const float* w_gate = (const float*)d_in[7];
  const float* b_gate = (const float*)d_in[8];
  const float* sink   = (const float*)d_in[9];
  const float* wog    = (const float*)d_in[10];
  const float* w_out  = (const float*)d_in[11];
  float* out = (float*)d_out;

  float* ws = (float*)d_ws;
  float* hc = ws;                    // 2048*256
  float* qb = hc + 2048 * 256;       // 2048*512  (t, h, d)
  float* kb = qb + 2048 * 512;       // 2048*64
  float* vb = kb + 2048 * 64;        // 2048*64
  float* kc = vb + 2048 * 64;        // 64*64
  float* vc = kc + 64 * 64;          // 64*64
  float* mx = vc + 64 * 64;          // 2048*512  (t, h, d)
  float* y1 = mx + 2048 * 512;       // 2048*1024

  dim3 blk(256);
  // hc = h @ w_qc
  gemm_tile<float, float, float><<<dim3(4, 32), blk, 0, stream>>>(h, w_qc, hc, 2048, 256, 1024, 1024, 256, 256);
  // q_raw = hc @ w_qup
  gemm_tile<float, float, float><<<dim3(8, 32), blk, 0, stream>>>(hc, w_qup, qb, 2048, 512, 256, 256, 512, 512);
  // k_raw = h @ w_k ; v = h @ w_v
  gemm_tile<float, float, float><<<dim3(1, 32), blk, 0, stream>>>(h, w_k, kb, 2048, 64, 1024, 1024, 64, 64);
  gemm_tile<float, float, float><<<dim3(1, 32), blk, 0, stream>>>(h, w_v, vb, 2048, 64, 1024, 1024, 64, 64);
  // RoPE + RMSNorm
  rope_rms_kernel<<<dim3(4096), blk, 0, stream>>>(qb, g_qn, 16384, 3);
  rope_rms_kernel<<<dim3(512), blk, 0, stream>>>(kb, g_kn, 2048, 0);
  // compressed K/V
  compress_kernel<<<dim3(64), dim3(64), 0, stream>>>(kb, vb, kc, vc);
  // attention (comp + selected + sliding window + gate mix)
  attn_kernel<<<dim3(4096), blk, 0, stream>>>(qb, kb, vb, kc, vc, w_gate, b_gate, sink, mx);
  // grouped projection: y1[:, g*512:(g+1)*512] = mx[:, g*256:(g+1)*256] @ wog[g]
  gemm_tile<float, float, float><<<dim3(8, 32), blk, 0, stream>>>(mx, wog, y1, 2048, 512, 256, 512, 512, 1024);
  gemm_tile<float, float, float><<<dim3(8, 32), blk, 0, stream>>>(mx + 256, wog + 256 * 512, y1 + 512, 2048, 512, 256, 512, 512, 1024);
  // out = y1 @ w_out  (f32 store)
  gemm_tile<float, float, float><<<dim3(16, 32), blk, 0, stream>>>(y1, w_out, out, 2048, 1024, 1024, 1024, 1024, 1024);
}

// Round 12
// 733.343 us; speedup vs baseline: 1.4836x; 1.4325x over previous
//
#include <hip/hip_runtime.h>
#include <hip/hip_bf16.h>
#include <float.h>
#include <math.h>

typedef __hip_bfloat16 bf16;

#define NEGBIG (-1e30f)

__device__ __forceinline__ float ldv(const bf16* p, int i) { return __bfloat162float(p[i]); }
__device__ __forceinline__ float ldv(const float* p, int i) { return p[i]; }
__device__ __forceinline__ void stv(float* p, int i, float v) { p[i] = v; }
__device__ __forceinline__ void stv(bf16* p, int i, float v) { p[i] = __float2bfloat16(v); }

__device__ __forceinline__ float wave_sum(float v) {
#pragma unroll
  for (int off = 32; off; off >>= 1) v += __shfl_xor(v, off, 64);
  return v;
}
__device__ __forceinline__ float wave_max(float v) {
#pragma unroll
  for (int off = 32; off; off >>= 1) v = fmaxf(v, __shfl_xor(v, off, 64));
  return v;
}

// ---------------- generic tiled GEMM: C(MxN) = A(MxK) @ B(KxN), f32 accum ----
template <typename TA, typename TB, typename TC>
__global__ __launch_bounds__(256) void gemm_tile(
    const TA* __restrict__ A, const TB* __restrict__ B, TC* __restrict__ C,
    int M, int N, int K, int lda, int ldb, int ldc)
{
  __shared__ float As[16][65];
  __shared__ float Bs[16][65];
  const int tid = threadIdx.x;
  const int tx = tid & 15, ty = tid >> 4;
  const int row0 = blockIdx.y * 64, col0 = blockIdx.x * 64;
  float acc[4][4] = {};
  for (int k0 = 0; k0 < K; k0 += 16) {
#pragma unroll
    for (int l = 0; l < 4; ++l) {
      int idx = tid + l * 256;
      int m = idx >> 4, kk = idx & 15;
      As[kk][m] = ldv(A, (row0 + m) * lda + k0 + kk);
      int kk2 = idx >> 6, n = idx & 63;
      Bs[kk2][n] = ldv(B, (k0 + kk2) * ldb + col0 + n);
    }
    __syncthreads();
#pragma unroll
    for (int kk = 0; kk < 16; ++kk) {
      float a[4], b[4];
#pragma unroll
      for (int i = 0; i < 4; ++i) a[i] = As[kk][ty * 4 + i];
#pragma unroll
      for (int j = 0; j < 4; ++j) b[j] = Bs[kk][tx * 4 + j];
#pragma unroll
      for (int i = 0; i < 4; ++i)
#pragma unroll
        for (int j = 0; j < 4; ++j) acc[i][j] += a[i] * b[j];
    }
    __syncthreads();
  }
#pragma unroll
  for (int i = 0; i < 4; ++i)
#pragma unroll
    for (int j = 0; j < 4; ++j)
      stv(C, (row0 + ty * 4 + i) * ldc + col0 + tx * 4 + j, acc[i][j]);
}

// ---------------- RoPE (first 32 dims) + RMSNorm, one wave per 64-dim row ----
// Optionally also writes a d4-group-major transposed copy xT4:
//   xT4 float layout: ((lane>>2)*rowsT + r)*4 + (lane&3)   (rowsT = total rows)
__global__ __launch_bounds__(256) void rope_rms_kernel(
    float* __restrict__ x, const float* __restrict__ g, int rows, int posShift,
    float* __restrict__ xT4)
{
  const int lane = threadIdx.x & 63;
  const int wid = threadIdx.x >> 6;
  const int r = blockIdx.x * 4 + wid;
  if (r >= rows) return;
  const int pos = r >> posShift;
  float val = x[r * 64 + lane];
  float p = __shfl_xor(val, 16, 64);
  float out = val;
  if (lane < 32) {
    int i = lane & 15;
    double ang = (double)pos * pow(10000.0, -(double)i / 16.0);
    float cc = (float)cos(ang), ss = (float)sin(ang);
    out = (lane < 16) ? (val * cc - p * ss) : (p * ss + val * cc);
  }
  float ms = wave_sum(out * out) * (1.0f / 64.0f);
  float rn = rsqrtf(ms + 1e-6f);
  float res = out * rn * ldv(g, lane);
  x[r * 64 + lane] = res;
  if (xT4) xT4[(lane >> 2) * (rows * 4) + r * 4 + (lane & 3)] = res;
}

// ---------------- block-mean compression: kcT4 (d4-major) + vc (row-major) ---
__global__ void compress_kernel(const float* __restrict__ k, const float* __restrict__ v,
                                float* __restrict__ kcT4, float* __restrict__ vc)
{
  const int n = blockIdx.x;   // block index 0..63
  const int d = threadIdx.x;  // dim 0..63
  float sk = 0.f, sv = 0.f;
  for (int j = 0; j < 32; ++j) {
    sk += k[(n * 32 + j) * 64 + d];
    sv += v[(n * 32 + j) * 64 + d];
  }
  kcT4[(d >> 2) * 256 + n * 4 + (d & 3)] = sk * (1.0f / 32.0f);
  vc[n * 64 + d] = sv * (1.0f / 32.0f);
}

// ---------------- attention: one wave per (qpos, head) -----------------------
// All QK loads COALESCED via d4-major transposed K (kT4[16][2048] float4,
// kcT4[16][64] float4): lane=token, 16B/lane consecutive. r5/r10/r11 showed
// VALUBusy pinned ~27% at any occupancy -> per-CU scattered-request path was
// saturated; this removes every scattered load. PV stays lane=dim (coalesced).
__global__ __launch_bounds__(256) void attn_kernel(
    const float* __restrict__ q, const float* __restrict__ kT4, const float* __restrict__ vbuf,
    const float* __restrict__ kcT4, const float* __restrict__ vc,
    const float* __restrict__ w_gate, const float* __restrict__ b_gate,
    const float* __restrict__ sink, float* __restrict__ mixed)
{
  __shared__ __align__(16) float shq[4][64];
  __shared__ int shsel[4][16];
  const int lane = threadIdx.x & 63;
  const int wid = threadIdx.x >> 6;
  const int r = blockIdx.x * 4 + wid;   // r = qpos*8 + h
  const int qpos = r >> 3, h = r & 7;
  const float scale = 0.125f;

  float qv = q[r * 64 + lane];
  shq[wid][lane] = qv;

  // ---- gate: sigmoid(q @ w_gate + b_gate), normalized ----
  float z0 = qv * ldv(w_gate, lane * 3 + 0);
  float z1 = qv * ldv(w_gate, lane * 3 + 1);
  float z2 = qv * ldv(w_gate, lane * 3 + 2);
  z0 = wave_sum(z0) + ldv(b_gate, 0);
  z1 = wave_sum(z1) + ldv(b_gate, 1);
  z2 = wave_sum(z2) + ldv(b_gate, 2);
  float ga0 = 1.f / (1.f + expf(-z0));
  float ga1 = 1.f / (1.f + expf(-z1));
  float ga2 = 1.f / (1.f + expf(-z2));
  float gs = fmaxf(ga0 + ga1 + ga2, 1e-6f);
  float ginv = 1.f / gs;
  ga0 *= ginv; ga1 *= ginv; ga2 *= ginv;

  const float4* qr = reinterpret_cast<const float4*>(&shq[wid][0]);
  const float4* kt = reinterpret_cast<const float4*>(kT4);    // [16][2048]
  const float4* kct = reinterpret_cast<const float4*>(kcT4);  // [16][64]
  const float snk = ldv(sink, h);
  const int nv = (qpos + 1) >> 5;  // valid compressed blocks

  // ---- compressed scores (lane = block index), coalesced ----
  float sc;
  {
    float d0 = 0.f, d1 = 0.f;
#pragma unroll 1
    for (int i = 0; i < 16; i += 2) {
      float4 q0 = qr[i],     k0 = kct[i * 64 + lane];
      float4 q1 = qr[i + 1], k1 = kct[(i + 1) * 64 + lane];
      d0 += q0.x * k0.x + q0.z * k0.z;
      d1 += q0.y * k0.y + q0.w * k0.w;
      d0 += q1.x * k1.x + q1.z * k1.z;
      d1 += q1.y * k1.y + q1.w * k1.w;
    }
    sc = (d0 + d1) * scale;
  }

  float comp_out = 0.f;
  if (nv > 0) {
    float scomp = (lane < nv) ? sc : NEGBIG;
    float m = fmaxf(wave_max(scomp), snk);
    float e = (lane < nv) ? expf(sc - m) : 0.f;
    float S = wave_sum(e) + expf(snk - m);
    float pn = e / S;   // zero for lane >= nv
    float c0 = 0.f, c1 = 0.f, c2 = 0.f, c3 = 0.f;
#pragma unroll 1
    for (int n = 0; n < 64; n += 4) {
      float p0 = __shfl(pn, n + 0, 64);
      float p1 = __shfl(pn, n + 1, 64);
      float p2 = __shfl(pn, n + 2, 64);
      float p3 = __shfl(pn, n + 3, 64);
      c0 += p0 * vc[(n + 0) * 64 + lane];
      c1 += p1 * vc[(n + 1) * 64 + lane];
      c2 += p2 * vc[(n + 2) * 64 + lane];
      c3 += p3 * vc[(n + 3) * 64 + lane];
    }
    comp_out = (c0 + c1) + (c2 + c3);
  }

  // ---- top-16 block selection (emulates jax.lax.top_k tie semantics) ----
  {
    float selv = (lane < nv) ? sc : -FLT_MAX;   // invalid = -FLT_MAX (picked by index order)
#pragma unroll
    for (int it = 0; it < 16; ++it) {
      float bv = selv; int bi = lane;
#pragma unroll
      for (int off = 32; off; off >>= 1) {
        float ov = __shfl_xor(bv, off, 64);
        int oi = __shfl_xor(bi, off, 64);
        if (ov > bv || (ov == bv && oi < bi)) { bv = ov; bi = oi; }
      }
      if (lane == 0) shsel[wid][it] = bi;
      if (lane == bi) selv = -INFINITY;         // removed, never re-picked
    }
  }

  // ---- selected branch: 8 chunks x 2 blocks (full-wave coalesced QK) ----
  float M = NEGBIG, S = 0.f, osel = 0.f;
#pragma unroll 1
  for (int c = 0; c < 8; ++c) {
    int b0 = shsel[wid][2 * c], b1 = shsel[wid][2 * c + 1];
    int base0 = b0 * 32, base1 = b1 * 32;
    if (base0 > qpos && base1 > qpos) continue;  // both blocks invalid: e==0, state unchanged
    int tok = ((lane < 32) ? base0 : base1) + (lane & 31);
    bool ok = (tok <= qpos);
    float d0 = 0.f, d1 = 0.f;
#pragma unroll 1
    for (int i = 0; i < 16; i += 2) {
      float4 q0 = qr[i],     k0 = kt[i * 2048 + tok];
      float4 q1 = qr[i + 1], k1 = kt[(i + 1) * 2048 + tok];
      d0 += q0.x * k0.x + q0.z * k0.z;
      d1 += q0.y * k0.y + q0.w * k0.w;
      d0 += q1.x * k1.x + q1.z * k1.z;
      d1 += q1.y * k1.y + q1.w * k1.w;
    }
    float s = ok ? (d0 + d1) * scale : NEGBIG;
    float Mn = fmaxf(M, wave_max(s));
    float e = ok ? expf(s - Mn) : 0.f;
    float cs = wave_sum(e);
    float corr = expf(M - Mn);
    S = S * corr + cs;
    float a0 = 0.f, a1 = 0.f, a2 = 0.f, a3 = 0.f;
#pragma unroll 1
    for (int l = 0; l < 32; l += 4) {
      float p0 = __shfl(e, l + 0, 64);
      float p1 = __shfl(e, l + 1, 64);
      float p2 = __shfl(e, l + 2, 64);
      float p3 = __shfl(e, l + 3, 64);
      a0 += p0 * vbuf[(base0 + l + 0) * 64 + lane];
      a1 += p1 * vbuf[(base0 + l + 1) * 64 + lane];
      a2 += p2 * vbuf[(base0 + l + 2) * 64 + lane];
      a3 += p3 * vbuf[(base0 + l + 3) * 64 + lane];
    }
#pragma unroll 1
    for (int l = 0; l < 32; l += 4) {
      float p0 = __shfl(e, 32 + l + 0, 64);
      float p1 = __shfl(e, 32 + l + 1, 64);
      float p2 = __shfl(e, 32 + l + 2, 64);
      float p3 = __shfl(e, 32 + l + 3, 64);
      a0 += p0 * vbuf[(base1 + l + 0) * 64 + lane];
      a1 += p1 * vbuf[(base1 + l + 1) * 64 + lane];
      a2 += p2 * vbuf[(base1 + l + 2) * 64 + lane];
      a3 += p3 * vbuf[(base1 + l + 3) * 64 + lane];
    }
    osel = osel * corr + ((a0 + a1) + (a2 + a3));
    M = Mn;
  }
  osel /= S;

  // ---- sliding-window branch (window 512, with sink), coalesced QK ----
  float Mw = NEGBIG, Sw = 0.f, osw = 0.f;
  int kstart = qpos - 511; if (kstart < 0) kstart = 0;
  int nch = (qpos - kstart + 64) >> 6;
#pragma unroll 1
  for (int c = 0; c < nch; ++c) {
    int base = kstart + c * 64;
    int tok = base + lane;
    bool ok = (tok <= qpos);
    float d0 = 0.f, d1 = 0.f;
#pragma unroll 1
    for (int i = 0; i < 16; i += 2) {
      float4 q0 = qr[i],     k0 = kt[i * 2048 + tok];
      float4 q1 = qr[i + 1], k1 = kt[(i + 1) * 2048 + tok];
      d0 += q0.x * k0.x + q0.z * k0.z;
      d1 += q0.y * k0.y + q0.w * k0.w;
      d0 += q1.x * k1.x + q1.z * k1.z;
      d1 += q1.y * k1.y + q1.w * k1.w;
    }
    float s = ok ? (d0 + d1) * scale : NEGBIG;
    float Mn = fmaxf(Mw, wave_max(s));
    float e = ok ? expf(s - Mn) : 0.f;
    float cs = wave_sum(e);
    float corr = expf(Mw - Mn);
    Sw = Sw * corr + cs;
    float a0 = 0.f, a1 = 0.f, a2 = 0.f, a3 = 0.f;
#pragma unroll 1
    for (int l = 0; l < 64; l += 4) {
      float p0 = __shfl(e, l + 0, 64);
      float p1 = __shfl(e, l + 1, 64);
      float p2 = __shfl(e, l + 2, 64);
      float p3 = __shfl(e, l + 3, 64);
      a0 += p0 * vbuf[(base + l + 0) * 64 + lane];
      a1 += p1 * vbuf[(base + l + 1) * 64 + lane];
      a2 += p2 * vbuf[(base + l + 2) * 64 + lane];
      a3 += p3 * vbuf[(base + l + 3) * 64 + lane];
    }
    osw = osw * corr + ((a0 + a1) + (a2 + a3));
    Mw = Mn;
  }
  {
    float Mf = fmaxf(Mw, snk);
    float corr = expf(Mw - Mf);
    float Sf = Sw * corr + expf(snk - Mf);
    osw = osw * corr / Sf;
  }

  mixed[r * 64 + lane] = ga0 * comp_out + ga1 * osel + ga2 * osw;
}

// ---------------- launch ----------------
extern "C" void kernel_launch(void* const* d_in, const int* in_sizes, int n_in,
                              void* d_out, int out_size, void* d_ws, size_t ws_size,
                              hipStream_t stream) {
  const float* h      = (const float*)d_in[0];
  const float* w_qc   = (const float*)d_in[1];
  const float* w_qup  = (const float*)d_in[2];
  const float* w_k    = (const float*)d_in[3];
  const float* w_v    = (const float*)d_in[4];
  const float* g_qn   = (const float*)d_in[5];
  const float* g_kn   = (const float*)d_in[6];
  const float* w_gate = (const float*)d_in[7];
  const float* b_gate = (const float*)d_in[8];
  const float* sink   = (const float*)d_in[9];
  const float* wog    = (const float*)d_in[10];
  const float* w_out  = (const float*)d_in[11];
  float* out = (float*)d_out;

  float* ws = (float*)d_ws;
  float* hc  = ws;                    // 2048*256
  float* qb  = hc + 2048 * 256;       // 2048*512  (t, h, d)
  float* kb  = qb + 2048 * 512;       // 2048*64
  float* vb  = kb + 2048 * 64;        // 2048*64
  float* vc  = vb + 2048 * 64;        // 64*64
  float* mx  = vc + 64 * 64;          // 2048*512  (t, h, d)
  float* y1  = mx + 2048 * 512;       // 2048*1024
  float* kt4 = y1 + 2048 * 1024;      // 16*2048*4 (d4-major K transpose)
  float* kct4 = kt4 + 16 * 2048 * 4;  // 16*64*4

  dim3 blk(256);
  // hc = h @ w_qc
  gemm_tile<float, float, float><<<dim3(4, 32), blk, 0, stream>>>(h, w_qc, hc, 2048, 256, 1024, 1024, 256, 256);
  // q_raw = hc @ w_qup
  gemm_tile<float, float, float><<<dim3(8, 32), blk, 0, stream>>>(hc, w_qup, qb, 2048, 512, 256, 256, 512, 512);
  // k_raw = h @ w_k ; v = h @ w_v
  gemm_tile<float, float, float><<<dim3(1, 32), blk, 0, stream>>>(h, w_k, kb, 2048, 64, 1024, 1024, 64, 64);
  gemm_tile<float, float, float><<<dim3(1, 32), blk, 0, stream>>>(h, w_v, vb, 2048, 64, 1024, 1024, 64, 64);
  // RoPE + RMSNorm (k also emits d4-major transpose)
  rope_rms_kernel<<<dim3(4096), blk, 0, stream>>>(qb, g_qn, 16384, 3, nullptr);
  rope_rms_kernel<<<dim3(512), blk, 0, stream>>>(kb, g_kn, 2048, 0, kt4);
  // compressed K (d4-major) / V
  compress_kernel<<<dim3(64), dim3(64), 0, stream>>>(kb, vb, kct4, vc);
  // attention (comp + selected + sliding window + gate mix)
  attn_kernel<<<dim3(4096), blk, 0, stream>>>(qb, kt4, vb, kct4, vc, w_gate, b_gate, sink, mx);
  // grouped projection: y1[:, g*512:(g+1)*512] = mx[:, g*256:(g+1)*256] @ wog[g]
  gemm_tile<float, float, float><<<dim3(8, 32), blk, 0, stream>>>(mx, wog, y1, 2048, 512, 256, 512, 512, 1024);
  gemm_tile<float, float, float><<<dim3(8, 32), blk, 0, stream>>>(mx + 256, wog + 256 * 512, y1 + 512, 2048, 512, 256, 512, 512, 1024);
  // out = y1 @ w_out  (f32 store)
  gemm_tile<float, float, float><<<dim3(16, 32), blk, 0, stream>>>(y1, w_out, out, 2048, 1024, 1024, 1024, 1024, 1024);
}

// Round 13
// 574.492 us; speedup vs baseline: 1.8938x; 1.2765x over previous
//
#include <hip/hip_runtime.h>
#include <hip/hip_bf16.h>
#include <float.h>
#include <math.h>

typedef __hip_bfloat16 bf16;

#define NEGBIG (-1e30f)

__device__ __forceinline__ float ldv(const float* p, int i) { return p[i]; }

__device__ __forceinline__ float wave_sum(float v) {
#pragma unroll
  for (int off = 32; off; off >>= 1) v += __shfl_xor(v, off, 64);
  return v;
}
__device__ __forceinline__ float wave_max(float v) {
#pragma unroll
  for (int off = 32; off; off >>= 1) v = fmaxf(v, __shfl_xor(v, off, 64));
  return v;
}

// ---------------- pipelined f32 GEMM: C(MxN) = A(MxK) @ B(KxN) ---------------
// 64x64 tile, 4x4 microtile, K-step 16. Double-buffered LDS, float4 staging,
// ONE barrier per K-step, b128 LDS reads (stride 68 keeps 16B alignment).
// FMA order per output identical to the old kernel -> bitwise-same results.
__global__ __launch_bounds__(256) void gemm_tile(
    const float* __restrict__ A, const float* __restrict__ B, float* __restrict__ C,
    int M, int N, int K, int lda, int ldb, int ldc)
{
  __shared__ __align__(16) float As[2][16][68];
  __shared__ __align__(16) float Bs[2][16][68];
  const int tid = threadIdx.x;
  const int tx = tid & 15, ty = tid >> 4;
  const int row0 = blockIdx.y * 64, col0 = blockIdx.x * 64;
  // staging: A tile 64 rows x 16 k (transposed into LDS), B tile 16 k x 64 cols
  const int ar = tid >> 2;          // A row 0..63
  const int ak = (tid & 3) * 4;     // A k-offset {0,4,8,12}
  const int bk = tid >> 4;          // B k-row 0..15
  const int bc = (tid & 15) * 4;    // B col offset

  const int nk = K >> 4;
  float4 a4 = *reinterpret_cast<const float4*>(&A[(row0 + ar) * lda + ak]);
  float4 b4 = *reinterpret_cast<const float4*>(&B[bk * ldb + col0 + bc]);
  {
    As[0][ak + 0][ar] = a4.x; As[0][ak + 1][ar] = a4.y;
    As[0][ak + 2][ar] = a4.z; As[0][ak + 3][ar] = a4.w;
    *reinterpret_cast<float4*>(&Bs[0][bk][bc]) = b4;
  }

  float acc[4][4] = {};
  for (int t = 0; t < nk; ++t) {
    const int cur = t & 1;
    if (t + 1 < nk) {
      int k0 = (t + 1) * 16;
      a4 = *reinterpret_cast<const float4*>(&A[(row0 + ar) * lda + k0 + ak]);
      b4 = *reinterpret_cast<const float4*>(&B[(k0 + bk) * ldb + col0 + bc]);
    }
    __syncthreads();
#pragma unroll
    for (int kk = 0; kk < 16; ++kk) {
      float4 av = *reinterpret_cast<const float4*>(&As[cur][kk][ty * 4]);
      float4 bv = *reinterpret_cast<const float4*>(&Bs[cur][kk][tx * 4]);
      float a[4] = {av.x, av.y, av.z, av.w};
      float b[4] = {bv.x, bv.y, bv.z, bv.w};
#pragma unroll
      for (int i = 0; i < 4; ++i)
#pragma unroll
        for (int j = 0; j < 4; ++j) acc[i][j] += a[i] * b[j];
    }
    if (t + 1 < nk) {
      const int nxt = cur ^ 1;
      As[nxt][ak + 0][ar] = a4.x; As[nxt][ak + 1][ar] = a4.y;
      As[nxt][ak + 2][ar] = a4.z; As[nxt][ak + 3][ar] = a4.w;
      *reinterpret_cast<float4*>(&Bs[nxt][bk][bc]) = b4;
    }
  }
#pragma unroll
  for (int i = 0; i < 4; ++i) {
    float4 o = make_float4(acc[i][0], acc[i][1], acc[i][2], acc[i][3]);
    *reinterpret_cast<float4*>(&C[(row0 + ty * 4 + i) * ldc + col0 + tx * 4]) = o;
  }
}

// ---------------- RoPE (first 32 dims) + RMSNorm, one wave per 64-dim row ----
// Optionally also writes a d4-group-major transposed copy xT4.
__global__ __launch_bounds__(256) void rope_rms_kernel(
    float* __restrict__ x, const float* __restrict__ g, int rows, int posShift,
    float* __restrict__ xT4)
{
  const int lane = threadIdx.x & 63;
  const int wid = threadIdx.x >> 6;
  const int r = blockIdx.x * 4 + wid;
  if (r >= rows) return;
  const int pos = r >> posShift;
  float val = x[r * 64 + lane];
  float p = __shfl_xor(val, 16, 64);
  float out = val;
  if (lane < 32) {
    int i = lane & 15;
    double ang = (double)pos * pow(10000.0, -(double)i / 16.0);
    float cc = (float)cos(ang), ss = (float)sin(ang);
    out = (lane < 16) ? (val * cc - p * ss) : (p * ss + val * cc);
  }
  float ms = wave_sum(out * out) * (1.0f / 64.0f);
  float rn = rsqrtf(ms + 1e-6f);
  float res = out * rn * ldv(g, lane);
  x[r * 64 + lane] = res;
  if (xT4) xT4[(lane >> 2) * (rows * 4) + r * 4 + (lane & 3)] = res;
}

// ---------------- block-mean compression: kcT4 (d4-major) + vc (row-major) ---
__global__ void compress_kernel(const float* __restrict__ k, const float* __restrict__ v,
                                float* __restrict__ kcT4, float* __restrict__ vc)
{
  const int n = blockIdx.x;   // block index 0..63
  const int d = threadIdx.x;  // dim 0..63
  float sk = 0.f, sv = 0.f;
  for (int j = 0; j < 32; ++j) {
    sk += k[(n * 32 + j) * 64 + d];
    sv += v[(n * 32 + j) * 64 + d];
  }
  kcT4[(d >> 2) * 256 + n * 4 + (d & 3)] = sk * (1.0f / 32.0f);
  vc[n * 64 + d] = sv * (1.0f / 32.0f);
}

// ---------------- attention: one wave per (qpos, head) -----------------------
// (unchanged from r12: coalesced QK via d4-major K, shfl-broadcast PV)
__global__ __launch_bounds__(256) void attn_kernel(
    const float* __restrict__ q, const float* __restrict__ kT4, const float* __restrict__ vbuf,
    const float* __restrict__ kcT4, const float* __restrict__ vc,
    const float* __restrict__ w_gate, const float* __restrict__ b_gate,
    const float* __restrict__ sink, float* __restrict__ mixed)
{
  __shared__ __align__(16) float shq[4][64];
  __shared__ int shsel[4][16];
  const int lane = threadIdx.x & 63;
  const int wid = threadIdx.x >> 6;
  const int r = blockIdx.x * 4 + wid;   // r = qpos*8 + h
  const int qpos = r >> 3, h = r & 7;
  const float scale = 0.125f;

  float qv = q[r * 64 + lane];
  shq[wid][lane] = qv;

  // ---- gate: sigmoid(q @ w_gate + b_gate), normalized ----
  float z0 = qv * ldv(w_gate, lane * 3 + 0);
  float z1 = qv * ldv(w_gate, lane * 3 + 1);
  float z2 = qv * ldv(w_gate, lane * 3 + 2);
  z0 = wave_sum(z0) + ldv(b_gate, 0);
  z1 = wave_sum(z1) + ldv(b_gate, 1);
  z2 = wave_sum(z2) + ldv(b_gate, 2);
  float ga0 = 1.f / (1.f + expf(-z0));
  float ga1 = 1.f / (1.f + expf(-z1));
  float ga2 = 1.f / (1.f + expf(-z2));
  float gs = fmaxf(ga0 + ga1 + ga2, 1e-6f);
  float ginv = 1.f / gs;
  ga0 *= ginv; ga1 *= ginv; ga2 *= ginv;

  const float4* qr = reinterpret_cast<const float4*>(&shq[wid][0]);
  const float4* kt = reinterpret_cast<const float4*>(kT4);    // [16][2048]
  const float4* kct = reinterpret_cast<const float4*>(kcT4);  // [16][64]
  const float snk = ldv(sink, h);
  const int nv = (qpos + 1) >> 5;  // valid compressed blocks

  // ---- compressed scores (lane = block index), coalesced ----
  float sc;
  {
    float d0 = 0.f, d1 = 0.f;
#pragma unroll 1
    for (int i = 0; i < 16; i += 2) {
      float4 q0 = qr[i],     k0 = kct[i * 64 + lane];
      float4 q1 = qr[i + 1], k1 = kct[(i + 1) * 64 + lane];
      d0 += q0.x * k0.x + q0.z * k0.z;
      d1 += q0.y * k0.y + q0.w * k0.w;
      d0 += q1.x * k1.x + q1.z * k1.z;
      d1 += q1.y * k1.y + q1.w * k1.w;
    }
    sc = (d0 + d1) * scale;
  }

  float comp_out = 0.f;
  if (nv > 0) {
    float scomp = (lane < nv) ? sc : NEGBIG;
    float m = fmaxf(wave_max(scomp), snk);
    float e = (lane < nv) ? expf(sc - m) : 0.f;
    float S = wave_sum(e) + expf(snk - m);
    float pn = e / S;   // zero for lane >= nv
    float c0 = 0.f, c1 = 0.f, c2 = 0.f, c3 = 0.f;
#pragma unroll 1
    for (int n = 0; n < 64; n += 4) {
      float p0 = __shfl(pn, n + 0, 64);
      float p1 = __shfl(pn, n + 1, 64);
      float p2 = __shfl(pn, n + 2, 64);
      float p3 = __shfl(pn, n + 3, 64);
      c0 += p0 * vc[(n + 0) * 64 + lane];
      c1 += p1 * vc[(n + 1) * 64 + lane];
      c2 += p2 * vc[(n + 2) * 64 + lane];
      c3 += p3 * vc[(n + 3) * 64 + lane];
    }
    comp_out = (c0 + c1) + (c2 + c3);
  }

  // ---- top-16 block selection (emulates jax.lax.top_k tie semantics) ----
  {
    float selv = (lane < nv) ? sc : -FLT_MAX;   // invalid = -FLT_MAX (picked by index order)
#pragma unroll
    for (int it = 0; it < 16; ++it) {
      float bv = selv; int bi = lane;
#pragma unroll
      for (int off = 32; off; off >>= 1) {
        float ov = __shfl_xor(bv, off, 64);
        int oi = __shfl_xor(bi, off, 64);
        if (ov > bv || (ov == bv && oi < bi)) { bv = ov; bi = oi; }
      }
      if (lane == 0) shsel[wid][it] = bi;
      if (lane == bi) selv = -INFINITY;         // removed, never re-picked
    }
  }

  // ---- selected branch: 8 chunks x 2 blocks (full-wave coalesced QK) ----
  float M = NEGBIG, S = 0.f, osel = 0.f;
#pragma unroll 1
  for (int c = 0; c < 8; ++c) {
    int b0 = shsel[wid][2 * c], b1 = shsel[wid][2 * c + 1];
    int base0 = b0 * 32, base1 = b1 * 32;
    if (base0 > qpos && base1 > qpos) continue;  // both blocks invalid: e==0, state unchanged
    int tok = ((lane < 32) ? base0 : base1) + (lane & 31);
    bool ok = (tok <= qpos);
    float d0 = 0.f, d1 = 0.f;
#pragma unroll 1
    for (int i = 0; i < 16; i += 2) {
      float4 q0 = qr[i],     k0 = kt[i * 2048 + tok];
      float4 q1 = qr[i + 1], k1 = kt[(i + 1) * 2048 + tok];
      d0 += q0.x * k0.x + q0.z * k0.z;
      d1 += q0.y * k0.y + q0.w * k0.w;
      d0 += q1.x * k1.x + q1.z * k1.z;
      d1 += q1.y * k1.y + q1.w * k1.w;
    }
    float s = ok ? (d0 + d1) * scale : NEGBIG;
    float Mn = fmaxf(M, wave_max(s));
    float e = ok ? expf(s - Mn) : 0.f;
    float cs = wave_sum(e);
    float corr = expf(M - Mn);
    S = S * corr + cs;
    float a0 = 0.f, a1 = 0.f, a2 = 0.f, a3 = 0.f;
#pragma unroll 1
    for (int l = 0; l < 32; l += 4) {
      float p0 = __shfl(e, l + 0, 64);
      float p1 = __shfl(e, l + 1, 64);
      float p2 = __shfl(e, l + 2, 64);
      float p3 = __shfl(e, l + 3, 64);
      a0 += p0 * vbuf[(base0 + l + 0) * 64 + lane];
      a1 += p1 * vbuf[(base0 + l + 1) * 64 + lane];
      a2 += p2 * vbuf[(base0 + l + 2) * 64 + lane];
      a3 += p3 * vbuf[(base0 + l + 3) * 64 + lane];
    }
#pragma unroll 1
    for (int l = 0; l < 32; l += 4) {
      float p0 = __shfl(e, 32 + l + 0, 64);
      float p1 = __shfl(e, 32 + l + 1, 64);
      float p2 = __shfl(e, 32 + l + 2, 64);
      float p3 = __shfl(e, 32 + l + 3, 64);
      a0 += p0 * vbuf[(base1 + l + 0) * 64 + lane];
      a1 += p1 * vbuf[(base1 + l + 1) * 64 + lane];
      a2 += p2 * vbuf[(base1 + l + 2) * 64 + lane];
      a3 += p3 * vbuf[(base1 + l + 3) * 64 + lane];
    }
    osel = osel * corr + ((a0 + a1) + (a2 + a3));
    M = Mn;
  }
  osel /= S;

  // ---- sliding-window branch (window 512, with sink), coalesced QK ----
  float Mw = NEGBIG, Sw = 0.f, osw = 0.f;
  int kstart = qpos - 511; if (kstart < 0) kstart = 0;
  int nch = (qpos - kstart + 64) >> 6;
#pragma unroll 1
  for (int c = 0; c < nch; ++c) {
    int base = kstart + c * 64;
    int tok = base + lane;
    bool ok = (tok <= qpos);
    float d0 = 0.f, d1 = 0.f;
#pragma unroll 1
    for (int i = 0; i < 16; i += 2) {
      float4 q0 = qr[i],     k0 = kt[i * 2048 + tok];
      float4 q1 = qr[i + 1], k1 = kt[(i + 1) * 2048 + tok];
      d0 += q0.x * k0.x + q0.z * k0.z;
      d1 += q0.y * k0.y + q0.w * k0.w;
      d0 += q1.x * k1.x + q1.z * k1.z;
      d1 += q1.y * k1.y + q1.w * k1.w;
    }
    float s = ok ? (d0 + d1) * scale : NEGBIG;
    float Mn = fmaxf(Mw, wave_max(s));
    float e = ok ? expf(s - Mn) : 0.f;
    float cs = wave_sum(e);
    float corr = expf(Mw - Mn);
    Sw = Sw * corr + cs;
    float a0 = 0.f, a1 = 0.f, a2 = 0.f, a3 = 0.f;
#pragma unroll 1
    for (int l = 0; l < 64; l += 4) {
      float p0 = __shfl(e, l + 0, 64);
      float p1 = __shfl(e, l + 1, 64);
      float p2 = __shfl(e, l + 2, 64);
      float p3 = __shfl(e, l + 3, 64);
      a0 += p0 * vbuf[(base + l + 0) * 64 + lane];
      a1 += p1 * vbuf[(base + l + 1) * 64 + lane];
      a2 += p2 * vbuf[(base + l + 2) * 64 + lane];
      a3 += p3 * vbuf[(base + l + 3) * 64 + lane];
    }
    osw = osw * corr + ((a0 + a1) + (a2 + a3));
    Mw = Mn;
  }
  {
    float Mf = fmaxf(Mw, snk);
    float corr = expf(Mw - Mf);
    float Sf = Sw * corr + expf(snk - Mf);
    osw = osw * corr / Sf;
  }

  mixed[r * 64 + lane] = ga0 * comp_out + ga1 * osel + ga2 * osw;
}

// ---------------- launch ----------------
extern "C" void kernel_launch(void* const* d_in, const int* in_sizes, int n_in,
                              void* d_out, int out_size, void* d_ws, size_t ws_size,
                              hipStream_t stream) {
  const float* h      = (const float*)d_in[0];
  const float* w_qc   = (const float*)d_in[1];
  const float* w_qup  = (const float*)d_in[2];
  const float* w_k    = (const float*)d_in[3];
  const float* w_v    = (const float*)d_in[4];
  const float* g_qn   = (const float*)d_in[5];
  const float* g_kn   = (const float*)d_in[6];
  const float* w_gate = (const float*)d_in[7];
  const float* b_gate = (const float*)d_in[8];
  const float* sink   = (const float*)d_in[9];
  const float* wog    = (const float*)d_in[10];
  const float* w_out  = (const float*)d_in[11];
  float* out = (float*)d_out;

  float* ws = (float*)d_ws;
  float* hc  = ws;                    // 2048*256
  float* qb  = hc + 2048 * 256;       // 2048*512  (t, h, d)
  float* kb  = qb + 2048 * 512;       // 2048*64
  float* vb  = kb + 2048 * 64;        // 2048*64
  float* vc  = vb + 2048 * 64;        // 64*64
  float* mx  = vc + 64 * 64;          // 2048*512  (t, h, d)
  float* y1  = mx + 2048 * 512;       // 2048*1024
  float* kt4 = y1 + 2048 * 1024;      // 16*2048*4 (d4-major K transpose)
  float* kct4 = kt4 + 16 * 2048 * 4;  // 16*64*4

  dim3 blk(256);
  // hc = h @ w_qc
  gemm_tile<<<dim3(4, 32), blk, 0, stream>>>(h, w_qc, hc, 2048, 256, 1024, 1024, 256, 256);
  // q_raw = hc @ w_qup
  gemm_tile<<<dim3(8, 32), blk, 0, stream>>>(hc, w_qup, qb, 2048, 512, 256, 256, 512, 512);
  // k_raw = h @ w_k ; v = h @ w_v
  gemm_tile<<<dim3(1, 32), blk, 0, stream>>>(h, w_k, kb, 2048, 64, 1024, 1024, 64, 64);
  gemm_tile<<<dim3(1, 32), blk, 0, stream>>>(h, w_v, vb, 2048, 64, 1024, 1024, 64, 64);
  // RoPE + RMSNorm (k also emits d4-major transpose)
  rope_rms_kernel<<<dim3(4096), blk, 0, stream>>>(qb, g_qn, 16384, 3, nullptr);
  rope_rms_kernel<<<dim3(512), blk, 0, stream>>>(kb, g_kn, 2048, 0, kt4);
  // compressed K (d4-major) / V
  compress_kernel<<<dim3(64), dim3(64), 0, stream>>>(kb, vb, kct4, vc);
  // attention (comp + selected + sliding window + gate mix)
  attn_kernel<<<dim3(4096), blk, 0, stream>>>(qb, kt4, vb, kct4, vc, w_gate, b_gate, sink, mx);
  // grouped projection: y1[:, g*512:(g+1)*512] = mx[:, g*256:(g+1)*256] @ wog[g]
  gemm_tile<<<dim3(8, 32), blk, 0, stream>>>(mx, wog, y1, 2048, 512, 256, 512, 512, 1024);
  gemm_tile<<<dim3(8, 32), blk, 0, stream>>>(mx + 256, wog + 256 * 512, y1 + 512, 2048, 512, 256, 512, 512, 1024);
  // out = y1 @ w_out  (f32 store)
  gemm_tile<<<dim3(16, 32), blk, 0, stream>>>(y1, w_out, out, 2048, 1024, 1024, 1024, 1024, 1024);
}

// Round 14
// 524.474 us; speedup vs baseline: 2.0744x; 1.0954x over previous
//
#include <hip/hip_runtime.h>
#include <hip/hip_bf16.h>
#include <float.h>
#include <math.h>

typedef __hip_bfloat16 bf16;

#define NEGBIG (-1e30f)

__device__ __forceinline__ float ldv(const float* p, int i) { return p[i]; }

__device__ __forceinline__ float wave_sum(float v) {
#pragma unroll
  for (int off = 32; off; off >>= 1) v += __shfl_xor(v, off, 64);
  return v;
}
__device__ __forceinline__ float wave_max(float v) {
#pragma unroll
  for (int off = 32; off; off >>= 1) v = fmaxf(v, __shfl_xor(v, off, 64));
  return v;
}

__device__ __forceinline__ float rdlane(float v, int l) {
  return __uint_as_float(__builtin_amdgcn_readlane(__float_as_uint(v), l));
}

// PV over 16 tokens: p = lanes L0..L0+15 of e (readlane, literal), V rows at
// vp + t*64 floats (imm offsets 0..3840B). 4 independent accumulator chains.
template <int L0>
__device__ __forceinline__ void pv16(const float* __restrict__ vp, float e,
                                     float& a0, float& a1, float& a2, float& a3) {
#pragma unroll
  for (int t = 0; t < 16; t += 4) {
    float p0 = rdlane(e, L0 + t + 0);
    float p1 = rdlane(e, L0 + t + 1);
    float p2 = rdlane(e, L0 + t + 2);
    float p3 = rdlane(e, L0 + t + 3);
    a0 += p0 * vp[(t + 0) * 64];
    a1 += p1 * vp[(t + 1) * 64];
    a2 += p2 * vp[(t + 2) * 64];
    a3 += p3 * vp[(t + 3) * 64];
  }
}

// QK dot against one 32-token K block slice: kp = &kS[sb*512 + (lane&31)],
// d4-row i at kp[i*32] (imm offsets; unroll-1 quads keep VGPR low).
__device__ __forceinline__ float qk_dot(const float4* __restrict__ qr,
                                        const float4* __restrict__ kp) {
  float d0 = 0.f, d1 = 0.f;
#pragma unroll 1
  for (int i = 0; i < 16; i += 4) {
    float4 q0 = qr[i],     k0 = kp[i * 32];
    float4 q1 = qr[i + 1], k1 = kp[i * 32 + 32];
    float4 q2 = qr[i + 2], k2 = kp[i * 32 + 64];
    float4 q3 = qr[i + 3], k3 = kp[i * 32 + 96];
    d0 += q0.x * k0.x + q0.z * k0.z;
    d1 += q0.y * k0.y + q0.w * k0.w;
    d0 += q1.x * k1.x + q1.z * k1.z;
    d1 += q1.y * k1.y + q1.w * k1.w;
    d0 += q2.x * k2.x + q2.z * k2.z;
    d1 += q2.y * k2.y + q2.w * k2.w;
    d0 += q3.x * k3.x + q3.z * k3.z;
    d1 += q3.y * k3.y + q3.w * k3.w;
  }
  return d0 + d1;
}

// ---------------- pipelined f32 GEMM (unchanged from r13) -------------------
__global__ __launch_bounds__(256) void gemm_tile(
    const float* __restrict__ A, const float* __restrict__ B, float* __restrict__ C,
    int M, int N, int K, int lda, int ldb, int ldc)
{
  __shared__ __align__(16) float As[2][16][68];
  __shared__ __align__(16) float Bs[2][16][68];
  const int tid = threadIdx.x;
  const int tx = tid & 15, ty = tid >> 4;
  const int row0 = blockIdx.y * 64, col0 = blockIdx.x * 64;
  const int ar = tid >> 2;
  const int ak = (tid & 3) * 4;
  const int bk = tid >> 4;
  const int bc = (tid & 15) * 4;

  const int nk = K >> 4;
  float4 a4 = *reinterpret_cast<const float4*>(&A[(row0 + ar) * lda + ak]);
  float4 b4 = *reinterpret_cast<const float4*>(&B[bk * ldb + col0 + bc]);
  {
    As[0][ak + 0][ar] = a4.x; As[0][ak + 1][ar] = a4.y;
    As[0][ak + 2][ar] = a4.z; As[0][ak + 3][ar] = a4.w;
    *reinterpret_cast<float4*>(&Bs[0][bk][bc]) = b4;
  }

  float acc[4][4] = {};
  for (int t = 0; t < nk; ++t) {
    const int cur = t & 1;
    if (t + 1 < nk) {
      int k0 = (t + 1) * 16;
      a4 = *reinterpret_cast<const float4*>(&A[(row0 + ar) * lda + k0 + ak]);
      b4 = *reinterpret_cast<const float4*>(&B[(k0 + bk) * ldb + col0 + bc]);
    }
    __syncthreads();
#pragma unroll
    for (int kk = 0; kk < 16; ++kk) {
      float4 av = *reinterpret_cast<const float4*>(&As[cur][kk][ty * 4]);
      float4 bv = *reinterpret_cast<const float4*>(&Bs[cur][kk][tx * 4]);
      float a[4] = {av.x, av.y, av.z, av.w};
      float b[4] = {bv.x, bv.y, bv.z, bv.w};
#pragma unroll
      for (int i = 0; i < 4; ++i)
#pragma unroll
        for (int j = 0; j < 4; ++j) acc[i][j] += a[i] * b[j];
    }
    if (t + 1 < nk) {
      const int nxt = cur ^ 1;
      As[nxt][ak + 0][ar] = a4.x; As[nxt][ak + 1][ar] = a4.y;
      As[nxt][ak + 2][ar] = a4.z; As[nxt][ak + 3][ar] = a4.w;
      *reinterpret_cast<float4*>(&Bs[nxt][bk][bc]) = b4;
    }
  }
#pragma unroll
  for (int i = 0; i < 4; ++i) {
    float4 o = make_float4(acc[i][0], acc[i][1], acc[i][2], acc[i][3]);
    *reinterpret_cast<float4*>(&C[(row0 + ty * 4 + i) * ldc + col0 + tx * 4]) = o;
  }
}

// ---------------- RoPE (first 32 dims) + RMSNorm ----------------------------
// Optionally writes block-local K copy kS[tok>>5][d>>2][tok&31] (float4 units).
__global__ __launch_bounds__(256) void rope_rms_kernel(
    float* __restrict__ x, const float* __restrict__ g, int rows, int posShift,
    float* __restrict__ kS)
{
  const int lane = threadIdx.x & 63;
  const int wid = threadIdx.x >> 6;
  const int r = blockIdx.x * 4 + wid;
  if (r >= rows) return;
  const int pos = r >> posShift;
  float val = x[r * 64 + lane];
  float p = __shfl_xor(val, 16, 64);
  float out = val;
  if (lane < 32) {
    int i = lane & 15;
    double ang = (double)pos * pow(10000.0, -(double)i / 16.0);
    float cc = (float)cos(ang), ss = (float)sin(ang);
    out = (lane < 16) ? (val * cc - p * ss) : (p * ss + val * cc);
  }
  float ms = wave_sum(out * out) * (1.0f / 64.0f);
  float rn = rsqrtf(ms + 1e-6f);
  float res = out * rn * ldv(g, lane);
  x[r * 64 + lane] = res;
  if (kS) {
    int f4 = (r >> 5) * 512 + (lane >> 2) * 32 + (r & 31);
    kS[f4 * 4 + (lane & 3)] = res;
  }
}

// ---------------- block-mean compression: kcT4 (d4-major) + vc --------------
__global__ void compress_kernel(const float* __restrict__ k, const float* __restrict__ v,
                                float* __restrict__ kcT4, float* __restrict__ vc)
{
  const int n = blockIdx.x;
  const int d = threadIdx.x;
  float sk = 0.f, sv = 0.f;
  for (int j = 0; j < 32; ++j) {
    sk += k[(n * 32 + j) * 64 + d];
    sv += v[(n * 32 + j) * 64 + d];
  }
  kcT4[(d >> 2) * 256 + n * 4 + (d & 3)] = sk * (1.0f / 32.0f);
  vc[n * 64 + d] = sv * (1.0f / 32.0f);
}

// ---------------- attention: one wave per (qpos, head) -----------------------
// Instruction-minimized: block-local K (imm-offset QK), readlane+imm-offset PV.
__global__ __launch_bounds__(256) void attn_kernel(
    const float* __restrict__ q, const float* __restrict__ kS, const float* __restrict__ vbuf,
    const float* __restrict__ kcT4, const float* __restrict__ vc,
    const float* __restrict__ w_gate, const float* __restrict__ b_gate,
    const float* __restrict__ sink, float* __restrict__ mixed)
{
  __shared__ __align__(16) float shq[4][64];
  __shared__ int shsel[4][16];
  const int lane = threadIdx.x & 63;
  const int wid = threadIdx.x >> 6;
  const int r = blockIdx.x * 4 + wid;   // r = qpos*8 + h
  const int qpos = r >> 3, h = r & 7;
  const float scale = 0.125f;

  float qv = q[r * 64 + lane];
  shq[wid][lane] = qv;

  // ---- gate ----
  float z0 = qv * ldv(w_gate, lane * 3 + 0);
  float z1 = qv * ldv(w_gate, lane * 3 + 1);
  float z2 = qv * ldv(w_gate, lane * 3 + 2);
  z0 = wave_sum(z0) + ldv(b_gate, 0);
  z1 = wave_sum(z1) + ldv(b_gate, 1);
  z2 = wave_sum(z2) + ldv(b_gate, 2);
  float ga0 = 1.f / (1.f + expf(-z0));
  float ga1 = 1.f / (1.f + expf(-z1));
  float ga2 = 1.f / (1.f + expf(-z2));
  float gs = fmaxf(ga0 + ga1 + ga2, 1e-6f);
  float ginv = 1.f / gs;
  ga0 *= ginv; ga1 *= ginv; ga2 *= ginv;

  const float4* qr = reinterpret_cast<const float4*>(&shq[wid][0]);
  const float4* ks4 = reinterpret_cast<const float4*>(kS);
  const float4* kct = reinterpret_cast<const float4*>(kcT4);  // [16][64]
  const float snk = ldv(sink, h);
  const int nv = (qpos + 1) >> 5;

  // ---- compressed scores (lane = block index) ----
  float sc;
  {
    float d0 = 0.f, d1 = 0.f;
#pragma unroll 1
    for (int i = 0; i < 16; i += 2) {
      float4 q0 = qr[i],     k0 = kct[i * 64 + lane];
      float4 q1 = qr[i + 1], k1 = kct[(i + 1) * 64 + lane];
      d0 += q0.x * k0.x + q0.z * k0.z;
      d1 += q0.y * k0.y + q0.w * k0.w;
      d0 += q1.x * k1.x + q1.z * k1.z;
      d1 += q1.y * k1.y + q1.w * k1.w;
    }
    sc = (d0 + d1) * scale;
  }

  float comp_out = 0.f;
  if (nv > 0) {
    float scomp = (lane < nv) ? sc : NEGBIG;
    float m = fmaxf(wave_max(scomp), snk);
    float e = (lane < nv) ? expf(sc - m) : 0.f;
    float S = wave_sum(e) + expf(snk - m);
    float pn = e / S;   // zero for lane >= nv
    const float* vcp = vc + lane;
    float c0 = 0.f, c1 = 0.f, c2 = 0.f, c3 = 0.f;
    pv16<0>(vcp, pn, c0, c1, c2, c3);
    pv16<16>(vcp + 1024, pn, c0, c1, c2, c3);
    pv16<32>(vcp + 2048, pn, c0, c1, c2, c3);
    pv16<48>(vcp + 3072, pn, c0, c1, c2, c3);
    comp_out = (c0 + c1) + (c2 + c3);
  }

  // ---- top-16 block selection (jax.lax.top_k tie semantics) ----
  {
    float selv = (lane < nv) ? sc : -FLT_MAX;
#pragma unroll
    for (int it = 0; it < 16; ++it) {
      float bv = selv; int bi = lane;
#pragma unroll
      for (int off = 32; off; off >>= 1) {
        float ov = __shfl_xor(bv, off, 64);
        int oi = __shfl_xor(bi, off, 64);
        if (ov > bv || (ov == bv && oi < bi)) { bv = ov; bi = oi; }
      }
      if (lane == 0) shsel[wid][it] = bi;
      if (lane == bi) selv = -INFINITY;
    }
  }

  // ---- selected branch: 8 chunks x 2 blocks ----
  float M = NEGBIG, S = 0.f, osel = 0.f;
#pragma unroll 1
  for (int c = 0; c < 8; ++c) {
    int b0 = shsel[wid][2 * c], b1 = shsel[wid][2 * c + 1];
    int base0 = b0 * 32, base1 = b1 * 32;
    if (base0 > qpos && base1 > qpos) continue;
    int myb = (lane < 32) ? b0 : b1;
    int tok = myb * 32 + (lane & 31);
    bool ok = (tok <= qpos);
    const float4* kp = ks4 + myb * 512 + (lane & 31);
    float s = ok ? qk_dot(qr, kp) * scale : NEGBIG;
    float Mn = fmaxf(M, wave_max(s));
    float e = ok ? expf(s - Mn) : 0.f;
    float cs = wave_sum(e);
    float corr = expf(M - Mn);
    S = S * corr + cs;
    const float* v0 = vbuf + base0 * 64 + lane;
    const float* v1 = vbuf + base1 * 64 + lane;
    float a0 = 0.f, a1 = 0.f, a2 = 0.f, a3 = 0.f;
    pv16<0>(v0, e, a0, a1, a2, a3);
    pv16<16>(v0 + 1024, e, a0, a1, a2, a3);
    pv16<32>(v1, e, a0, a1, a2, a3);
    pv16<48>(v1 + 1024, e, a0, a1, a2, a3);
    osel = osel * corr + ((a0 + a1) + (a2 + a3));
    M = Mn;
  }
  osel /= S;

  // ---- sliding-window branch: aligned 32-token sub-blocks, 2 per iter ----
  float Mw = NEGBIG, Sw = 0.f, osw = 0.f;
  int kstart = qpos - 511; if (kstart < 0) kstart = 0;
  int sbf = kstart >> 5, sbl = qpos >> 5;
#pragma unroll 1
  for (int sb = sbf; sb <= sbl; sb += 2) {
    int sb1 = sb + 1;
    bool v1ok = (sb1 <= sbl);
    int sb1c = v1ok ? sb1 : sb;            // clamp for safe loads
    int myb = (lane < 32) ? sb : sb1c;
    int tok = myb * 32 + (lane & 31);
    bool ok = (tok >= kstart) && (tok <= qpos) && ((lane < 32) || v1ok);
    const float4* kp = ks4 + myb * 512 + (lane & 31);
    float s = ok ? qk_dot(qr, kp) * scale : NEGBIG;
    float Mn = fmaxf(Mw, wave_max(s));
    float e = ok ? expf(s - Mn) : 0.f;
    float cs = wave_sum(e);
    float corr = expf(Mw - Mn);
    Sw = Sw * corr + cs;
    const float* v0 = vbuf + sb * 2048 + lane;    // sb*32*64
    const float* v1 = vbuf + sb1c * 2048 + lane;
    float a0 = 0.f, a1 = 0.f, a2 = 0.f, a3 = 0.f;
    pv16<0>(v0, e, a0, a1, a2, a3);
    pv16<16>(v0 + 1024, e, a0, a1, a2, a3);
    pv16<32>(v1, e, a0, a1, a2, a3);
    pv16<48>(v1 + 1024, e, a0, a1, a2, a3);
    osw = osw * corr + ((a0 + a1) + (a2 + a3));
    Mw = Mn;
  }
  {
    float Mf = fmaxf(Mw, snk);
    float corr = expf(Mw - Mf);
    float Sf = Sw * corr + expf(snk - Mf);
    osw = osw * corr / Sf;
  }

  mixed[r * 64 + lane] = ga0 * comp_out + ga1 * osel + ga2 * osw;
}

// ---------------- launch ----------------
extern "C" void kernel_launch(void* const* d_in, const int* in_sizes, int n_in,
                              void* d_out, int out_size, void* d_ws, size_t ws_size,
                              hipStream_t stream) {
  const float* h      = (const float*)d_in[0];
  const float* w_qc   = (const float*)d_in[1];
  const float* w_qup  = (const float*)d_in[2];
  const float* w_k    = (const float*)d_in[3];
  const float* w_v    = (const float*)d_in[4];
  const float* g_qn   = (const float*)d_in[5];
  const float* g_kn   = (const float*)d_in[6];
  const float* w_gate = (const float*)d_in[7];
  const float* b_gate = (const float*)d_in[8];
  const float* sink   = (const float*)d_in[9];
  const float* wog    = (const float*)d_in[10];
  const float* w_out  = (const float*)d_in[11];
  float* out = (float*)d_out;

  float* ws = (float*)d_ws;
  float* hc  = ws;                    // 2048*256
  float* qb  = hc + 2048 * 256;       // 2048*512
  float* kb  = qb + 2048 * 512;       // 2048*64
  float* vb  = kb + 2048 * 64;        // 2048*64
  float* vc  = vb + 2048 * 64;        // 64*64
  float* mx  = vc + 64 * 64;          // 2048*512
  float* y1  = mx + 2048 * 512;       // 2048*1024
  float* kS  = y1 + 2048 * 1024;      // 2048*64 block-local K
  float* kct4 = kS + 2048 * 64;       // 16*64*4

  dim3 blk(256);
  gemm_tile<<<dim3(4, 32), blk, 0, stream>>>(h, w_qc, hc, 2048, 256, 1024, 1024, 256, 256);
  gemm_tile<<<dim3(8, 32), blk, 0, stream>>>(hc, w_qup, qb, 2048, 512, 256, 256, 512, 512);
  gemm_tile<<<dim3(1, 32), blk, 0, stream>>>(h, w_k, kb, 2048, 64, 1024, 1024, 64, 64);
  gemm_tile<<<dim3(1, 32), blk, 0, stream>>>(h, w_v, vb, 2048, 64, 1024, 1024, 64, 64);
  rope_rms_kernel<<<dim3(4096), blk, 0, stream>>>(qb, g_qn, 16384, 3, nullptr);
  rope_rms_kernel<<<dim3(512), blk, 0, stream>>>(kb, g_kn, 2048, 0, kS);
  compress_kernel<<<dim3(64), dim3(64), 0, stream>>>(kb, vb, kct4, vc);
  attn_kernel<<<dim3(4096), blk, 0, stream>>>(qb, kS, vb, kct4, vc, w_gate, b_gate, sink, mx);
  gemm_tile<<<dim3(8, 32), blk, 0, stream>>>(mx, wog, y1, 2048, 512, 256, 512, 512, 1024);
  gemm_tile<<<dim3(8, 32), blk, 0, stream>>>(mx + 256, wog + 256 * 512, y1 + 512, 2048, 512, 256, 512, 512, 1024);
  gemm_tile<<<dim3(16, 32), blk, 0, stream>>>(y1, w_out, out, 2048, 1024, 1024, 1024, 1024, 1024);
}